// Round 10
// baseline (177.373 us; speedup 1.0000x reference)
//
#include <hip/hip_runtime.h>

constexpr int Sc = 4096, Dc = 64;
constexpr int BH = 128;
constexpr int SS = 8;                     // s-split chunks in k1
constexpr int CHUNK = Sc / SS;            // 512 rows per block
constexpr int SROWS = 32;                 // s-rows per stage (one MFMA K-step)
constexpr int NST = CHUNK / SROWS;        // 16 stages
constexpr int MM = Dc * Dc;               // 4096 floats of M per (bh)
constexpr int LSTR = 66;                  // bf16 elems per LDS row (pad 2: bank spread)
constexpr int NZC = SS * SROWS;           // 256 z partial groups
constexpr int QT = 128;                   // q-rows per block in k3

using sh8 = __attribute__((ext_vector_type(8))) short;
using f32x4 = __attribute__((ext_vector_type(4))) float;

__device__ __forceinline__ unsigned int packbf2(float lo, float hi) {
  // two RNE float->bf16 packed into one dword
  unsigned int a = __builtin_bit_cast(unsigned int, lo);
  unsigned int b = __builtin_bit_cast(unsigned int, hi);
  a = (a + 0x7fffu + ((a >> 16) & 1u)) >> 16;
  b = (b + 0x7fffu + ((b >> 16) & 1u)) & 0xffff0000u;
  return a | b;
}

// ---- Kernel 1: M = K^T V per (bh,chunk) via bf16 MFMA; depth-3 prefetch pipeline ----
// 4 register sets, loads issued 3 stages ahead of consumption; LDS write of stage
// st+1 at end of iter st waits on loads issued at iter st-2 (~2.3 stages > HBM lat).
__global__ __launch_bounds__(256) void k1_accum(const float* __restrict__ K,
                                                const float* __restrict__ V,
                                                float* __restrict__ Pm,
                                                double* __restrict__ Pz) {
  const int blk = blockIdx.x, bh = blk >> 3, ck = blk & 7;
  const int tid = threadIdx.x, w = tid >> 6, l = tid & 63;
  const int g = l >> 4, c = l & 15;
  const int s_l = tid >> 3, dblk = tid & 7;     // staging: row s_l, floats d=8*dblk..+7

  const size_t base = ((size_t)bh * Sc + (size_t)ck * CHUNK) * Dc;
  const float4* gk4 = (const float4*)(K + base);
  const float4* gv4 = (const float4*)(V + base);
  const int ldi = s_l * 16 + dblk * 2;          // float4 index within a 32-row stage

  __shared__ __align__(16) unsigned short lk[2][SROWS * LSTR];
  __shared__ __align__(16) unsigned short lv[2][SROWS * LSTR];

  f32x4 acc[4];
  #pragma unroll
  for (int i = 0; i < 4; ++i) acc[i] = (f32x4){0.f, 0.f, 0.f, 0.f};
  double zacc[8] = {};

  // 4 static prefetch sets (stage s lives in set s&3)
  float4 k0a, k0b, v0a, v0b, k1a, k1b, v1a, v1b;
  float4 k2a, k2b, v2a, v2b, k3a, k3b, v3a, v3b;

#define K1_LOADSET(KA, KB, VA, VB, ST)                                       \
  {                                                                          \
    const int o_ = (ST) * (SROWS * 16);                                      \
    KA = gk4[o_ + ldi]; KB = gk4[o_ + ldi + 1];                              \
    VA = gv4[o_ + ldi]; VB = gv4[o_ + ldi + 1];                              \
  }

#define K1_WRITESET(KA, KB, VA, VB, BUF)                                     \
  {                                                                          \
    unsigned int* dk = (unsigned int*)&lk[BUF][s_l * LSTR + dblk * 8];       \
    dk[0] = packbf2(KA.x, KA.y); dk[1] = packbf2(KA.z, KA.w);                \
    dk[2] = packbf2(KB.x, KB.y); dk[3] = packbf2(KB.z, KB.w);                \
    unsigned int* dv = (unsigned int*)&lv[BUF][s_l * LSTR + dblk * 8];       \
    dv[0] = packbf2(VA.x, VA.y); dv[1] = packbf2(VA.z, VA.w);                \
    dv[2] = packbf2(VB.x, VB.y); dv[3] = packbf2(VB.z, VB.w);                \
    zacc[0] += (double)KA.x; zacc[1] += (double)KA.y;                        \
    zacc[2] += (double)KA.z; zacc[3] += (double)KA.w;                        \
    zacc[4] += (double)KB.x; zacc[5] += (double)KB.y;                        \
    zacc[6] += (double)KB.z; zacc[7] += (double)KB.w;                        \
  }

#define K1_COMPUTE(BUF)                                                      \
  {                                                                          \
    const unsigned short* plk = lk[BUF];                                     \
    const unsigned short* plv = lv[BUF];                                     \
    sh8 afr;                                                                 \
    _Pragma("unroll")                                                        \
    for (int j = 0; j < 8; ++j)                                              \
      afr[j] = (short)plk[(8 * g + j) * LSTR + 16 * w + c];                  \
    _Pragma("unroll")                                                        \
    for (int et = 0; et < 4; ++et) {                                         \
      sh8 bfr;                                                               \
      _Pragma("unroll")                                                      \
      for (int j = 0; j < 8; ++j)                                            \
        bfr[j] = (short)plv[(8 * g + j) * LSTR + 16 * et + c];               \
      acc[et] = __builtin_amdgcn_mfma_f32_16x16x32_bf16(afr, bfr, acc[et], 0, 0, 0); \
    }                                                                        \
  }

  // prologue: stages 0,1,2 -> sets 0,1,2; stage 0 staged into LDS buf 0
  K1_LOADSET(k0a, k0b, v0a, v0b, 0)
  K1_LOADSET(k1a, k1b, v1a, v1b, 1)
  K1_LOADSET(k2a, k2b, v2a, v2b, 2)
  K1_WRITESET(k0a, k0b, v0a, v0b, 0)
  __syncthreads();

  for (int stb = 0; stb < NST; stb += 4) {
    // iter st=stb+0: load set3<-st+3, compute buf0, write set1(st+1)->buf1
    if (stb + 3 < NST) K1_LOADSET(k3a, k3b, v3a, v3b, stb + 3)
    K1_COMPUTE(0)
    if (stb + 1 < NST) K1_WRITESET(k1a, k1b, v1a, v1b, 1)
    __syncthreads();
    // iter st=stb+1: load set0<-st+4, compute buf1, write set2(st+2)->buf0
    if (stb + 4 < NST) K1_LOADSET(k0a, k0b, v0a, v0b, stb + 4)
    K1_COMPUTE(1)
    if (stb + 2 < NST) K1_WRITESET(k2a, k2b, v2a, v2b, 0)
    __syncthreads();
    // iter st=stb+2: load set1<-st+5, compute buf0, write set3(st+3)->buf1
    if (stb + 5 < NST) K1_LOADSET(k1a, k1b, v1a, v1b, stb + 5)
    K1_COMPUTE(0)
    if (stb + 3 < NST) K1_WRITESET(k3a, k3b, v3a, v3b, 1)
    __syncthreads();
    // iter st=stb+3: load set2<-st+6, compute buf1, write set0(st+4)->buf0
    if (stb + 6 < NST) K1_LOADSET(k2a, k2b, v2a, v2b, stb + 6)
    K1_COMPUTE(1)
    if (stb + 4 < NST) K1_WRITESET(k0a, k0b, v0a, v0b, 0)
    __syncthreads();
  }
#undef K1_LOADSET
#undef K1_WRITESET
#undef K1_COMPUTE

  // Pm partial: D layout col=lane&15, row=(lane>>4)*4+reg
  float* pd = Pm + ((size_t)ck * BH + bh) * MM;
  #pragma unroll
  for (int et = 0; et < 4; ++et)
    #pragma unroll
    for (int r = 0; r < 4; ++r)
      pd[(16 * w + 4 * g + r) * 64 + 16 * et + c] = acc[et][r];

  // z partials: group = ck*32 + s_l, cols d = 8*dblk..+7
  double* pz = Pz + ((size_t)ck * SROWS + s_l) * (size_t)(BH * 64) +
               (size_t)bh * 64 + dblk * 8;
  #pragma unroll
  for (int j = 0; j < 8; ++j) pz[j] = zacc[j];
}

// ---- Kernel 2: reduce M partials (f32); z = f64 exact sum ROUNDED TO F32 ----
__global__ __launch_bounds__(256) void k2_reduce(const float* __restrict__ Pm,
                                                 const double* __restrict__ Pz,
                                                 float* __restrict__ Fm,
                                                 float* __restrict__ Fz) {
  const int i = blockIdx.x * 256 + threadIdx.x;
  const int nm = BH * MM;
  if (i < nm) {
    float s = 0.f;
    #pragma unroll
    for (int cc = 0; cc < SS; ++cc) s += Pm[(size_t)cc * nm + i];
    Fm[i] = s;
  }
  const int nz = BH * Dc;
  if (i < nz) {
    double s = 0.0;
    for (int cc = 0; cc < NZC; ++cc) s += Pz[(size_t)cc * nz + i];
    Fz[i] = (float)s;   // f32 intermediate matches np bitwise
  }
}

// ---- Kernel 3: out = (q @ M) / (q . z_f32 + eps); 4 rows x 8 cols per thread ----
__global__ __launch_bounds__(256) void k3_retrieve(const float* __restrict__ Q,
                                                   const float* __restrict__ Fm,
                                                   const float* __restrict__ Fz,
                                                   float* __restrict__ O) {
  const int blk = blockIdx.x;             // BH * (Sc/QT) = 128*32
  const int bh = blk >> 5;
  const int row0 = (blk & 31) * QT;

  __shared__ __align__(16) float lm[Dc][Dc];     // 16 KB
  __shared__ __align__(16) float lq[QT][68];     // padded: row stride 68 floats
  __shared__ __align__(16) float lz[Dc];         // f32 z (the np intermediate)

  const int tid = threadIdx.x;

  // stage M: contiguous 16 KB
  const float4* gm4 = (const float4*)(Fm + (size_t)bh * MM);
  float4* lm4 = (float4*)&lm[0][0];
  #pragma unroll
  for (int j = 0; j < 4; ++j) lm4[tid + j * 256] = gm4[tid + j * 256];
  if (tid < Dc) lz[tid] = Fz[(size_t)bh * Dc + tid];

  // stage q rows (coalesced global, padded LDS rows)
  const float4* gq4 = (const float4*)(Q + ((size_t)bh * Sc + row0) * Dc);
  #pragma unroll
  for (int j = 0; j < 8; ++j) {
    const int i4 = tid + j * 256;
    const float4 v = gq4[i4];
    const int f = i4 * 4;
    *(float4*)&lq[f >> 6][f & 63] = v;
  }
  __syncthreads();

  const int rg = tid >> 3;       // 0..31 -> row quad
  const int cg = tid & 7;        // 0..7  -> 8-col block
  const int r0 = rg * 4;
  const int e0 = cg * 8;

  float acc[4][8] = {};
  double den[4] = {0.0, 0.0, 0.0, 0.0};

  #pragma unroll
  for (int ds = 0; ds < 16; ++ds) {
    const int d0 = ds * 4;
    const float4 z4 = *(const float4*)&lz[d0];
    const float* zf = (const float*)&z4;
    float4 q4[4];
    #pragma unroll
    for (int r = 0; r < 4; ++r) q4[r] = *(const float4*)&lq[r0 + r][d0];
    const float* qf[4] = {(const float*)&q4[0], (const float*)&q4[1],
                          (const float*)&q4[2], (const float*)&q4[3]};
    #pragma unroll
    for (int i = 0; i < 4; ++i) {
      const float4 ma = *(const float4*)&lm[d0 + i][e0];
      const float4 mb = *(const float4*)&lm[d0 + i][e0 + 4];
      const float mf[8] = {ma.x, ma.y, ma.z, ma.w, mb.x, mb.y, mb.z, mb.w};
      const double zd = (double)zf[i];
      #pragma unroll
      for (int r = 0; r < 4; ++r) {
        const float qs = qf[r][i];
        den[r] += (double)qs * zd;
        #pragma unroll
        for (int j = 0; j < 8; ++j)
          acc[r][j] = fmaf(qs, mf[j], acc[r][j]);
      }
    }
  }

  #pragma unroll
  for (int r = 0; r < 4; ++r) {
    const double iv = 1.0 / (den[r] + 1e-6);
    float* go = O + ((size_t)bh * Sc + row0 + r0 + r) * Dc + e0;
    ((float4*)go)[0] = make_float4((float)((double)acc[r][0] * iv),
                                   (float)((double)acc[r][1] * iv),
                                   (float)((double)acc[r][2] * iv),
                                   (float)((double)acc[r][3] * iv));
    ((float4*)go)[1] = make_float4((float)((double)acc[r][4] * iv),
                                   (float)((double)acc[r][5] * iv),
                                   (float)((double)acc[r][6] * iv),
                                   (float)((double)acc[r][7] * iv));
  }
}

extern "C" void kernel_launch(void* const* d_in, const int* in_sizes, int n_in,
                              void* d_out, int out_size, void* d_ws, size_t ws_size,
                              hipStream_t stream) {
  const float* K = (const float*)d_in[0];   // keys    [B,H,S,D]
  const float* V = (const float*)d_in[1];   // values
  const float* Q = (const float*)d_in[2];   // queries
  float* O = (float*)d_out;                 // [B,H,S,D]

  float* Pm = (float*)d_ws;                                  // SS*BH*MM floats   (16.8 MB)
  float* Fm = Pm + (size_t)SS * BH * MM;                     // BH*MM floats      (2.1 MB)
  double* Pz = (double*)(Fm + (size_t)BH * MM);              // NZC*BH*Dc doubles (16.8 MB)
  float* Fz = (float*)(Pz + (size_t)NZC * BH * Dc);          // BH*Dc floats      (32 KB)

  hipLaunchKernelGGL(k1_accum, dim3(BH * SS), dim3(256), 0, stream, K, V, Pm, Pz);
  hipLaunchKernelGGL(k2_reduce, dim3((BH * MM + 255) / 256), dim3(256), 0, stream, Pm, Pz, Fm, Fz);
  hipLaunchKernelGGL(k3_retrieve, dim3(BH * (Sc / QT)), dim3(256), 0, stream, Q, Fm, Fz, O);
}

// Round 11
// 169.002 us; speedup vs baseline: 1.0495x; 1.0495x over previous
//
#include <hip/hip_runtime.h>

constexpr int Sc = 4096, Dc = 64;
constexpr int BH = 128;
constexpr int SS = 8;                     // s-split chunks in k1
constexpr int CHUNK = Sc / SS;            // 512 rows per block
constexpr int SROWS = 32;                 // s-rows per stage (one MFMA K-step)
constexpr int NST = CHUNK / SROWS;        // 16 stages
constexpr int MM = Dc * Dc;               // 4096 floats of M per (bh)
constexpr int NZP = SS * 4;               // 32 z partials (per g-group)
constexpr int QT = 128;                   // q-rows per block in k3

using sh8 = __attribute__((ext_vector_type(8))) short;
using f32x4 = __attribute__((ext_vector_type(4))) float;

__device__ __forceinline__ unsigned int packbf2(float lo, float hi) {
  // two RNE float->bf16 packed into one dword (same numerics as R9/R10 pass)
  unsigned int a = __builtin_bit_cast(unsigned int, lo);
  unsigned int b = __builtin_bit_cast(unsigned int, hi);
  a = (a + 0x7fffu + ((a >> 16) & 1u)) >> 16;
  b = (b + 0x7fffu + ((b >> 16) & 1u)) & 0xffff0000u;
  return a | b;
}

// ---- Kernel 1: M = K^T V via bf16 MFMA, fragments gathered DIRECTLY from global ----
// No LDS, no barriers, no cross-wave deps: each lane loads exactly its fragment
// elements (64B-coalesced per 16-lane group; V 4x wave redundancy -> L1 hits).
// 40 independent loads/lane/stage -> deep MLP; TLP (16 waves/CU) hides HBM latency.
__global__ __launch_bounds__(256) void k1_accum(const float* __restrict__ K,
                                                const float* __restrict__ V,
                                                float* __restrict__ Pm,
                                                double* __restrict__ Pz) {
  const int blk = blockIdx.x, bh = blk >> 3, ck = blk & 7;
  const int tid = threadIdx.x, w = tid >> 6, l = tid & 63;
  const int g = l >> 4, c = l & 15;

  const size_t base = ((size_t)bh * Sc + (size_t)ck * CHUNK) * Dc;
  // lane-fixed columns: A reads K[.][16w+c]; B reads V[.][16et+c]
  const float* kcol = K + base + 16 * w + c;
  const float* vcol = V + base + c;

  f32x4 acc[4];
  #pragma unroll
  for (int i = 0; i < 4; ++i) acc[i] = (f32x4){0.f, 0.f, 0.f, 0.f};
  double zacc = 0.0;

  for (int st = 0; st < NST; ++st) {
    const int rowf = (st * SROWS + 8 * g) * Dc;   // float offset of this lane's 8-row slab

    float ak[8];
    #pragma unroll
    for (int j = 0; j < 8; ++j) ak[j] = kcol[rowf + j * Dc];

    float bv[4][8];
    #pragma unroll
    for (int et = 0; et < 4; ++et)
      #pragma unroll
      for (int j = 0; j < 8; ++j) bv[et][j] = vcol[rowf + j * Dc + 16 * et];

    // z partial: lane owns d = 16w+c, rows 8g..8g+8 of this stage (f64, order-free)
    #pragma unroll
    for (int j = 0; j < 8; ++j) zacc += (double)ak[j];

    // pack to bf16 fragments (RNE, identical to staged path)
    unsigned int au[4];
    #pragma unroll
    for (int j = 0; j < 4; ++j) au[j] = packbf2(ak[2 * j], ak[2 * j + 1]);
    const sh8 afr = __builtin_bit_cast(sh8, *(const uint4*)au);

    #pragma unroll
    for (int et = 0; et < 4; ++et) {
      unsigned int bu[4];
      #pragma unroll
      for (int j = 0; j < 4; ++j) bu[j] = packbf2(bv[et][2 * j], bv[et][2 * j + 1]);
      const sh8 bfr = __builtin_bit_cast(sh8, *(const uint4*)bu);
      acc[et] = __builtin_amdgcn_mfma_f32_16x16x32_bf16(afr, bfr, acc[et], 0, 0, 0);
    }
  }

  // Pm partial: D layout col=lane&15 -> e=16et+c, row=(lane>>4)*4+reg -> d=16w+4g+r
  float* pd = Pm + ((size_t)ck * BH + bh) * MM;
  #pragma unroll
  for (int et = 0; et < 4; ++et)
    #pragma unroll
    for (int r = 0; r < 4; ++r)
      pd[(16 * w + 4 * g + r) * 64 + 16 * et + c] = acc[et][r];

  // z partial p = ck*4 + g, component d = 16w + c  (each (p,d) written once)
  Pz[((size_t)(ck * 4 + g) * BH + bh) * Dc + 16 * w + c] = zacc;
}

// ---- Kernel 2: reduce M partials (f32); z = f64 exact sum ROUNDED TO F32 ----
__global__ __launch_bounds__(256) void k2_reduce(const float* __restrict__ Pm,
                                                 const double* __restrict__ Pz,
                                                 float* __restrict__ Fm,
                                                 float* __restrict__ Fz) {
  const int i = blockIdx.x * 256 + threadIdx.x;
  const int nm = BH * MM;
  if (i < nm) {
    float s = 0.f;
    #pragma unroll
    for (int cc = 0; cc < SS; ++cc) s += Pm[(size_t)cc * nm + i];
    Fm[i] = s;
  }
  const int nz = BH * Dc;
  if (i < nz) {
    double s = 0.0;
    #pragma unroll
    for (int cc = 0; cc < NZP; ++cc) s += Pz[(size_t)cc * nz + i];
    Fz[i] = (float)s;   // f32 intermediate matches np bitwise
  }
}

// ---- Kernel 3: out = (q @ M) / (q . z_f32 + eps); 4 rows x 8 cols per thread ----
__global__ __launch_bounds__(256) void k3_retrieve(const float* __restrict__ Q,
                                                   const float* __restrict__ Fm,
                                                   const float* __restrict__ Fz,
                                                   float* __restrict__ O) {
  const int blk = blockIdx.x;             // BH * (Sc/QT) = 128*32
  const int bh = blk >> 5;
  const int row0 = (blk & 31) * QT;

  __shared__ __align__(16) float lm[Dc][Dc];     // 16 KB
  __shared__ __align__(16) float lq[QT][68];     // padded: row stride 68 floats
  __shared__ __align__(16) float lz[Dc];         // f32 z (the np intermediate)

  const int tid = threadIdx.x;

  // stage M: contiguous 16 KB
  const float4* gm4 = (const float4*)(Fm + (size_t)bh * MM);
  float4* lm4 = (float4*)&lm[0][0];
  #pragma unroll
  for (int j = 0; j < 4; ++j) lm4[tid + j * 256] = gm4[tid + j * 256];
  if (tid < Dc) lz[tid] = Fz[(size_t)bh * Dc + tid];

  // stage q rows (coalesced global, padded LDS rows)
  const float4* gq4 = (const float4*)(Q + ((size_t)bh * Sc + row0) * Dc);
  #pragma unroll
  for (int j = 0; j < 8; ++j) {
    const int i4 = tid + j * 256;
    const float4 v = gq4[i4];
    const int f = i4 * 4;
    *(float4*)&lq[f >> 6][f & 63] = v;
  }
  __syncthreads();

  const int rg = tid >> 3;       // 0..31 -> row quad
  const int cg = tid & 7;        // 0..7  -> 8-col block
  const int r0 = rg * 4;
  const int e0 = cg * 8;

  float acc[4][8] = {};
  double den[4] = {0.0, 0.0, 0.0, 0.0};

  #pragma unroll
  for (int ds = 0; ds < 16; ++ds) {
    const int d0 = ds * 4;
    const float4 z4 = *(const float4*)&lz[d0];
    const float* zf = (const float*)&z4;
    float4 q4[4];
    #pragma unroll
    for (int r = 0; r < 4; ++r) q4[r] = *(const float4*)&lq[r0 + r][d0];
    const float* qf[4] = {(const float*)&q4[0], (const float*)&q4[1],
                          (const float*)&q4[2], (const float*)&q4[3]};
    #pragma unroll
    for (int i = 0; i < 4; ++i) {
      const float4 ma = *(const float4*)&lm[d0 + i][e0];
      const float4 mb = *(const float4*)&lm[d0 + i][e0 + 4];
      const float mf[8] = {ma.x, ma.y, ma.z, ma.w, mb.x, mb.y, mb.z, mb.w};
      const double zd = (double)zf[i];
      #pragma unroll
      for (int r = 0; r < 4; ++r) {
        const float qs = qf[r][i];
        den[r] += (double)qs * zd;
        #pragma unroll
        for (int j = 0; j < 8; ++j)
          acc[r][j] = fmaf(qs, mf[j], acc[r][j]);
      }
    }
  }

  #pragma unroll
  for (int r = 0; r < 4; ++r) {
    const double iv = 1.0 / (den[r] + 1e-6);
    float* go = O + ((size_t)bh * Sc + row0 + r0 + r) * Dc + e0;
    ((float4*)go)[0] = make_float4((float)((double)acc[r][0] * iv),
                                   (float)((double)acc[r][1] * iv),
                                   (float)((double)acc[r][2] * iv),
                                   (float)((double)acc[r][3] * iv));
    ((float4*)go)[1] = make_float4((float)((double)acc[r][4] * iv),
                                   (float)((double)acc[r][5] * iv),
                                   (float)((double)acc[r][6] * iv),
                                   (float)((double)acc[r][7] * iv));
  }
}

extern "C" void kernel_launch(void* const* d_in, const int* in_sizes, int n_in,
                              void* d_out, int out_size, void* d_ws, size_t ws_size,
                              hipStream_t stream) {
  const float* K = (const float*)d_in[0];   // keys    [B,H,S,D]
  const float* V = (const float*)d_in[1];   // values
  const float* Q = (const float*)d_in[2];   // queries
  float* O = (float*)d_out;                 // [B,H,S,D]

  float* Pm = (float*)d_ws;                                  // SS*BH*MM floats   (16.8 MB)
  float* Fm = Pm + (size_t)SS * BH * MM;                     // BH*MM floats      (2.1 MB)
  double* Pz = (double*)(Fm + (size_t)BH * MM);              // NZP*BH*Dc doubles (2.1 MB)
  float* Fz = (float*)(Pz + (size_t)NZP * BH * Dc);          // BH*Dc floats      (32 KB)

  hipLaunchKernelGGL(k1_accum, dim3(BH * SS), dim3(256), 0, stream, K, V, Pm, Pz);
  hipLaunchKernelGGL(k2_reduce, dim3((BH * MM + 255) / 256), dim3(256), 0, stream, Pm, Pz, Fm, Fz);
  hipLaunchKernelGGL(k3_retrieve, dim3(BH * (Sc / QT)), dim3(256), 0, stream, Q, Fm, Fz, O);
}

// Round 13
// 167.003 us; speedup vs baseline: 1.0621x; 1.0120x over previous
//
#include <hip/hip_runtime.h>

constexpr int Sc = 4096, Dc = 64;
constexpr int BH = 128;
constexpr int SS = 8;                     // s-split chunks in k1
constexpr int CHUNK = Sc / SS;            // 512 rows per block
constexpr int SROWS = 32;                 // s-rows per stage (one MFMA K-step)
constexpr int NST = CHUNK / SROWS;        // 16 stages
constexpr int MM = Dc * Dc;               // 4096 floats of M per (bh)
constexpr int NZP = SS * 4;               // 32 z partials (per g-group)
constexpr int QT = 128;                   // q-rows per block in k3

using sh8 = __attribute__((ext_vector_type(8))) short;
using f32x4 = __attribute__((ext_vector_type(4))) float;

__device__ __forceinline__ unsigned int packbf2(float lo, float hi) {
  // two RNE float->bf16 packed into one dword (bit-identical to R9/R10/R11 pass)
  unsigned int a = __builtin_bit_cast(unsigned int, lo);
  unsigned int b = __builtin_bit_cast(unsigned int, hi);
  a = (a + 0x7fffu + ((a >> 16) & 1u)) >> 16;
  b = (b + 0x7fffu + ((b >> 16) & 1u)) & 0xffff0000u;
  return a | b;
}

// ---- Kernel 1: M = K^T V via bf16 MFMA, direct-global fragment gather, ----
// ---- explicit 2-deep NAMED register double-buffer (no LDS, no barriers) ----
// The named sets force ~80 load destinations live -> deep MLP; R11's VGPR=56
// showed the compiler otherwise serializes the 40 loads/stage into ~5 chunks.
__global__ __launch_bounds__(256) void k1_accum(const float* __restrict__ K,
                                                const float* __restrict__ V,
                                                float* __restrict__ Pm,
                                                double* __restrict__ Pz) {
  const int blk = blockIdx.x, bh = blk >> 3, ck = blk & 7;
  const int tid = threadIdx.x, w = tid >> 6, l = tid & 63;
  const int g = l >> 4, c = l & 15;

  const size_t base = ((size_t)bh * Sc + (size_t)ck * CHUNK) * Dc;
  const float* kcol = K + base + 16 * w + c;   // A column d = 16w + c
  const float* vcol = V + base + c;            // B columns e = 16et + c

  f32x4 acc[4];
  #pragma unroll
  for (int i = 0; i < 4; ++i) acc[i] = (f32x4){0.f, 0.f, 0.f, 0.f};
  double zacc = 0.0;

  // two named prefetch sets (static indexing -> registers)
  float akA[8], bvA[4][8], akB[8], bvB[4][8];

#define K1_LOAD(AK, BV, ST)                                                  \
  {                                                                          \
    const int rowf_ = ((ST) * SROWS + 8 * g) * Dc;                           \
    _Pragma("unroll")                                                        \
    for (int j = 0; j < 8; ++j) AK[j] = kcol[rowf_ + j * Dc];                \
    _Pragma("unroll")                                                        \
    for (int et = 0; et < 4; ++et)                                           \
      _Pragma("unroll")                                                      \
      for (int j = 0; j < 8; ++j)                                            \
        BV[et][j] = vcol[rowf_ + j * Dc + 16 * et];                          \
  }

#define K1_COMP(AK, BV)                                                      \
  {                                                                          \
    _Pragma("unroll")                                                        \
    for (int j = 0; j < 8; ++j) zacc += (double)AK[j];                       \
    unsigned int au[4];                                                      \
    _Pragma("unroll")                                                        \
    for (int j = 0; j < 4; ++j) au[j] = packbf2(AK[2 * j], AK[2 * j + 1]);   \
    const sh8 afr = __builtin_bit_cast(sh8, *(const uint4*)au);              \
    _Pragma("unroll")                                                        \
    for (int et = 0; et < 4; ++et) {                                         \
      unsigned int bu[4];                                                    \
      _Pragma("unroll")                                                      \
      for (int j = 0; j < 4; ++j)                                            \
        bu[j] = packbf2(BV[et][2 * j], BV[et][2 * j + 1]);                   \
      const sh8 bfr = __builtin_bit_cast(sh8, *(const uint4*)bu);            \
      acc[et] = __builtin_amdgcn_mfma_f32_16x16x32_bf16(afr, bfr, acc[et], 0, 0, 0); \
    }                                                                        \
  }

  K1_LOAD(akA, bvA, 0)
  for (int st = 0; st < NST; st += 2) {
    K1_LOAD(akB, bvB, st + 1)                    // issue B loads before consuming A
    K1_COMP(akA, bvA)
    if (st + 2 < NST) K1_LOAD(akA, bvA, st + 2)  // issue next A before consuming B
    K1_COMP(akB, bvB)
  }
#undef K1_LOAD
#undef K1_COMP

  // Pm partial: D layout col=lane&15 -> e=16et+c, row=(lane>>4)*4+r -> d=16w+4g+r
  float* pd = Pm + ((size_t)ck * BH + bh) * MM;
  #pragma unroll
  for (int et = 0; et < 4; ++et)
    #pragma unroll
    for (int r = 0; r < 4; ++r)
      pd[(16 * w + 4 * g + r) * 64 + 16 * et + c] = acc[et][r];

  // z partial p = ck*4 + g, component d = 16w + c (each (p,d) written once)
  Pz[((size_t)(ck * 4 + g) * BH + bh) * Dc + 16 * w + c] = zacc;
}

// ---- Kernel 2: reduce M partials (f32); z = f64 exact sum ROUNDED TO F32 ----
__global__ __launch_bounds__(256) void k2_reduce(const float* __restrict__ Pm,
                                                 const double* __restrict__ Pz,
                                                 float* __restrict__ Fm,
                                                 float* __restrict__ Fz) {
  const int i = blockIdx.x * 256 + threadIdx.x;
  const int nm = BH * MM;
  if (i < nm) {
    float s = 0.f;
    #pragma unroll
    for (int cc = 0; cc < SS; ++cc) s += Pm[(size_t)cc * nm + i];
    Fm[i] = s;
  }
  const int nz = BH * Dc;
  if (i < nz) {
    double s = 0.0;
    #pragma unroll
    for (int cc = 0; cc < NZP; ++cc) s += Pz[(size_t)cc * nz + i];
    Fz[i] = (float)s;   // f32 intermediate matches np bitwise
  }
}

// ---- Kernel 3: out = (q @ M) / (q . z_f32 + eps); 4 rows x 8 cols per thread ----
__global__ __launch_bounds__(256) void k3_retrieve(const float* __restrict__ Q,
                                                   const float* __restrict__ Fm,
                                                   const float* __restrict__ Fz,
                                                   float* __restrict__ O) {
  const int blk = blockIdx.x;             // BH * (Sc/QT) = 128*32
  const int bh = blk >> 5;
  const int row0 = (blk & 31) * QT;

  __shared__ __align__(16) float lm[Dc][Dc];     // 16 KB
  __shared__ __align__(16) float lq[QT][68];     // padded: row stride 68 floats
  __shared__ __align__(16) float lz[Dc];         // f32 z (the np intermediate)

  const int tid = threadIdx.x;

  // stage M: contiguous 16 KB
  const float4* gm4 = (const float4*)(Fm + (size_t)bh * MM);
  float4* lm4 = (float4*)&lm[0][0];
  #pragma unroll
  for (int j = 0; j < 4; ++j) lm4[tid + j * 256] = gm4[tid + j * 256];
  if (tid < Dc) lz[tid] = Fz[(size_t)bh * Dc + tid];

  // stage q rows (coalesced global, padded LDS rows)
  const float4* gq4 = (const float4*)(Q + ((size_t)bh * Sc + row0) * Dc);
  #pragma unroll
  for (int j = 0; j < 8; ++j) {
    const int i4 = tid + j * 256;
    const float4 v = gq4[i4];
    const int f = i4 * 4;
    *(float4*)&lq[f >> 6][f & 63] = v;
  }
  __syncthreads();

  const int rg = tid >> 3;       // 0..31 -> row quad
  const int cg = tid & 7;        // 0..7  -> 8-col block
  const int r0 = rg * 4;
  const int e0 = cg * 8;

  float acc[4][8] = {};
  double den[4] = {0.0, 0.0, 0.0, 0.0};

  #pragma unroll
  for (int ds = 0; ds < 16; ++ds) {
    const int d0 = ds * 4;
    const float4 z4 = *(const float4*)&lz[d0];
    const float* zf = (const float*)&z4;
    float4 q4[4];
    #pragma unroll
    for (int r = 0; r < 4; ++r) q4[r] = *(const float4*)&lq[r0 + r][d0];
    const float* qf[4] = {(const float*)&q4[0], (const float*)&q4[1],
                          (const float*)&q4[2], (const float*)&q4[3]};
    #pragma unroll
    for (int i = 0; i < 4; ++i) {
      const float4 ma = *(const float4*)&lm[d0 + i][e0];
      const float4 mb = *(const float4*)&lm[d0 + i][e0 + 4];
      const float mf[8] = {ma.x, ma.y, ma.z, ma.w, mb.x, mb.y, mb.z, mb.w};
      const double zd = (double)zf[i];
      #pragma unroll
      for (int r = 0; r < 4; ++r) {
        const float qs = qf[r][i];
        den[r] += (double)qs * zd;
        #pragma unroll
        for (int j = 0; j < 8; ++j)
          acc[r][j] = fmaf(qs, mf[j], acc[r][j]);
      }
    }
  }

  #pragma unroll
  for (int r = 0; r < 4; ++r) {
    const double iv = 1.0 / (den[r] + 1e-6);
    float* go = O + ((size_t)bh * Sc + row0 + r0 + r) * Dc + e0;
    ((float4*)go)[0] = make_float4((float)((double)acc[r][0] * iv),
                                   (float)((double)acc[r][1] * iv),
                                   (float)((double)acc[r][2] * iv),
                                   (float)((double)acc[r][3] * iv));
    ((float4*)go)[1] = make_float4((float)((double)acc[r][4] * iv),
                                   (float)((double)acc[r][5] * iv),
                                   (float)((double)acc[r][6] * iv),
                                   (float)((double)acc[r][7] * iv));
  }
}

extern "C" void kernel_launch(void* const* d_in, const int* in_sizes, int n_in,
                              void* d_out, int out_size, void* d_ws, size_t ws_size,
                              hipStream_t stream) {
  const float* K = (const float*)d_in[0];   // keys    [B,H,S,D]
  const float* V = (const float*)d_in[1];   // values
  const float* Q = (const float*)d_in[2];   // queries
  float* O = (float*)d_out;                 // [B,H,S,D]

  float* Pm = (float*)d_ws;                                  // SS*BH*MM floats   (16.8 MB)
  float* Fm = Pm + (size_t)SS * BH * MM;                     // BH*MM floats      (2.1 MB)
  double* Pz = (double*)(Fm + (size_t)BH * MM);              // NZP*BH*Dc doubles (2.1 MB)
  float* Fz = (float*)(Pz + (size_t)NZP * BH * Dc);          // BH*Dc floats      (32 KB)

  hipLaunchKernelGGL(k1_accum, dim3(BH * SS), dim3(256), 0, stream, K, V, Pm, Pz);
  hipLaunchKernelGGL(k2_reduce, dim3((BH * MM + 255) / 256), dim3(256), 0, stream, Pm, Pz, Fm, Fz);
  hipLaunchKernelGGL(k3_retrieve, dim3(BH * (Sc / QT)), dim3(256), 0, stream, Q, Fm, Fz, O);
}